// Round 1
// baseline (382.865 us; speedup 1.0000x reference)
//
#include <hip/hip_runtime.h>
#include <cstdint>
#include <cstddef>

typedef float  f32x4   __attribute__((ext_vector_type(4)));
typedef __bf16 bf16x8  __attribute__((ext_vector_type(8)));
typedef short  short4_t __attribute__((ext_vector_type(4)));
typedef short  short8_t __attribute__((ext_vector_type(8)));

__device__ __forceinline__ short f2bf(float f) {
  uint32_t u = __builtin_bit_cast(uint32_t, f);
  u += 0x7fffu + ((u >> 16) & 1u);           // RNE
  return (short)(u >> 16);
}

__device__ __forceinline__ void gl_lds16(const void* g, void* l) {
  __builtin_amdgcn_global_load_lds((const __attribute__((address_space(1))) void*)g,
                                   (__attribute__((address_space(3))) void*)l, 16, 0, 0);
}

// ---------------- elementwise fp32 -> bf16 ----------------
__global__ void convert_bf16(const float* __restrict__ X, short* __restrict__ Xb) {
  int i = (blockIdx.x * 256 + threadIdx.x) * 4;
  f32x4 v = *(const f32x4*)&X[i];
  short4_t o;
#pragma unroll
  for (int j = 0; j < 4; j++) o[j] = f2bf(v[j]);
  *(short4_t*)&Xb[i] = o;
}

// ---------------- transpose-convert W[K][N] fp32 -> WT[N][K] bf16 ----------------
__global__ void transpose_bf16(const float* __restrict__ W, short* __restrict__ WT,
                               int K, int N) {
  __shared__ float tile[32][33];
  int tx = threadIdx.x & 31, ty = threadIdx.x >> 5;    // ty 0..7
  int n0 = blockIdx.x * 32, k0 = blockIdx.y * 32;
#pragma unroll
  for (int i = 0; i < 32; i += 8)
    tile[ty + i][tx] = W[(size_t)(k0 + ty + i) * N + n0 + tx];
  __syncthreads();
#pragma unroll
  for (int i = 0; i < 32; i += 8)
    WT[(size_t)(n0 + ty + i) * K + k0 + tx] = f2bf(tile[tx][ty + i]);
}

// ---------------- m97-style bf16 GEMM, Bt is [N][K] ----------------
// MODE 0: fp32 out [M][N].  MODE 1: scatter bf16 into Q/K/V [B,H,T,D].
template <int MODE>
__global__ __launch_bounds__(256, 2) void gemm_bt(
    const short* __restrict__ A, const short* __restrict__ Bt,
    float* __restrict__ outf, short* __restrict__ Qo, short* __restrict__ Ko,
    short* __restrict__ Vo, int M, int N, int K) {
  __shared__ alignas(16) short As[128 * 32];
  __shared__ alignas(16) short Bs[128 * 32];
  const int tid = threadIdx.x;
  const int lane = tid & 63, wave = tid >> 6;
  const int g = lane & 15, q = lane >> 4;
  const int m0 = blockIdx.y * 128, n0 = blockIdx.x * 128;
  const int wm = (wave >> 1) * 64, wn = (wave & 1) * 64;

  const int srow = tid >> 2;            // 0..63
  const int scol = (tid & 3) * 8;       // element col within BK
  const short* ap0 = A  + (size_t)(m0 + srow) * K + scol;
  const short* ap1 = A  + (size_t)(m0 + 64 + srow) * K + scol;
  const short* bp0 = Bt + (size_t)(n0 + srow) * K + scol;
  const short* bp1 = Bt + (size_t)(n0 + 64 + srow) * K + scol;
  short* la0 = &As[tid * 8];
  short* la1 = &As[(tid + 256) * 8];
  short* lb0 = &Bs[tid * 8];
  short* lb1 = &Bs[(tid + 256) * 8];

  f32x4 acc[4][4] = {};

  for (int k0 = 0; k0 < K; k0 += 32) {
    __syncthreads();
    gl_lds16(ap0 + k0, la0);
    gl_lds16(ap1 + k0, la1);
    gl_lds16(bp0 + k0, lb0);
    gl_lds16(bp1 + k0, lb1);
    __syncthreads();
    bf16x8 af[4], bfr[4];
#pragma unroll
    for (int mt = 0; mt < 4; mt++)
      af[mt] = *(const bf16x8*)&As[(wm + mt * 16 + g) * 32 + q * 8];
#pragma unroll
    for (int nt = 0; nt < 4; nt++)
      bfr[nt] = *(const bf16x8*)&Bs[(wn + nt * 16 + g) * 32 + q * 8];
#pragma unroll
    for (int mt = 0; mt < 4; mt++)
#pragma unroll
      for (int nt = 0; nt < 4; nt++)
        acc[mt][nt] = __builtin_amdgcn_mfma_f32_16x16x32_bf16(af[mt], bfr[nt],
                                                              acc[mt][nt], 0, 0, 0);
  }

  if (MODE == 0) {
#pragma unroll
    for (int mt = 0; mt < 4; mt++)
#pragma unroll
      for (int nt = 0; nt < 4; nt++) {
        int n = n0 + wn + nt * 16 + g;
        int mbase = m0 + wm + mt * 16 + q * 4;
#pragma unroll
        for (int r = 0; r < 4; r++)
          outf[(size_t)(mbase + r) * N + n] = acc[mt][nt][r];
      }
  } else {
#pragma unroll
    for (int nt = 0; nt < 4; nt++) {
      int n = n0 + wn + nt * 16 + g;
      int which = n >> 10;            // 0=q 1=k 2=v
      int c = n & 1023;
      int h = c >> 6, d = c & 63;
      short* dst = (which == 0) ? Qo : (which == 1) ? Ko : Vo;
#pragma unroll
      for (int mt = 0; mt < 4; mt++) {
        int mbase = m0 + wm + mt * 16 + q * 4;
#pragma unroll
        for (int r = 0; r < 4; r++) {
          int m = mbase + r;
          int b = m >> 11, t = m & 2047;
          dst[((size_t)((b << 4) + h) * 2048 + t) * 64 + d] = f2bf(acc[mt][nt][r]);
        }
      }
    }
  }
}

// ---------------- causal flash attention ----------------
// Q,K,V: [B,H,T,D] bf16.  O: [B,T,H,D] bf16 (== [8192,1024] row-major).
// Per block: one (b,h), 128 q-rows. Computes S^T = K*Q^T so q-rows land in the
// C-layout column (lane&15): softmax reduce = 2 shuffles, P stores row-packed.
__global__ __launch_bounds__(256, 2) void attn_fwd(
    const short* __restrict__ Qg, const short* __restrict__ Kg,
    const short* __restrict__ Vg, short* __restrict__ Og) {
  __shared__ alignas(16) short Ps[4][32 * 136];   // per-wave P [32][128+8]; also Q staging
  __shared__ alignas(16) short Ks[128 * 72];      // K tile [128][64+8]
  __shared__ alignas(16) short VTs[64 * 136];     // V^T [64][128+8]

  const int tid = threadIdx.x, lane = tid & 63, wave = tid >> 6;
  const int g = lane & 15, q = lane >> 4;
  const int qt = blockIdx.x, bh = blockIdx.y;
  const size_t base = (size_t)bh * (2048 * 64);
  const short* Qp = Qg + base + (size_t)qt * 128 * 64;

  // stage Q tile into Ps area as [128][72], pull frags into registers
  short* Qs = &Ps[0][0];
#pragma unroll
  for (int i = 0; i < 4; i++) {
    int c = tid + i * 256;
    int row = c >> 3, d0 = (c & 7) * 8;
    *(short8_t*)&Qs[row * 72 + d0] = *(const short8_t*)&Qp[row * 64 + d0];
  }
  __syncthreads();
  bf16x8 bq[2][2];
#pragma unroll
  for (int nt = 0; nt < 2; nt++)
#pragma unroll
    for (int kk = 0; kk < 2; kk++)
      bq[nt][kk] = *(const bf16x8*)&Qs[(wave * 32 + nt * 16 + g) * 72 + kk * 32 + q * 8];
  __syncthreads();

  f32x4 ot[4][2] = {};                 // O^T acc: [d-tiles 4][qrow-tiles 2]
  float m_run[2] = {-1e30f, -1e30f};
  float l_run[2] = {0.0f, 0.0f};
  const float cs = 0.18033688011f;     // (1/sqrt(64)) * log2(e)

  for (int kt = 0; kt <= qt; kt++) {
    __syncthreads();
    const short* Kp = Kg + base + (size_t)kt * 128 * 64;
    const short* Vp = Vg + base + (size_t)kt * 128 * 64;
#pragma unroll
    for (int i = 0; i < 4; i++) {
      int c = tid + i * 256;
      int row = c >> 3, d0 = (c & 7) * 8;
      *(short8_t*)&Ks[row * 72 + d0] = *(const short8_t*)&Kp[row * 64 + d0];
      short8_t v = *(const short8_t*)&Vp[row * 64 + d0];
#pragma unroll
      for (int j = 0; j < 8; j++) VTs[(d0 + j) * 136 + row] = v[j];
    }
    __syncthreads();

    // S^T = K * Q^T : rows=keys (8 tiles), cols=qrows (2 tiles)
    f32x4 st[8][2] = {};
#pragma unroll
    for (int kk = 0; kk < 2; kk++)
#pragma unroll
      for (int mt = 0; mt < 8; mt++) {
        bf16x8 ak = *(const bf16x8*)&Ks[(mt * 16 + g) * 72 + kk * 32 + q * 8];
#pragma unroll
        for (int nt = 0; nt < 2; nt++)
          st[mt][nt] = __builtin_amdgcn_mfma_f32_16x16x32_bf16(ak, bq[nt][kk],
                                                               st[mt][nt], 0, 0, 0);
      }

    const bool diag = (kt == qt);
    const int kb = kt * 128;
    const int qb = qt * 128 + wave * 32;
#pragma unroll
    for (int nt = 0; nt < 2; nt++) {
      const int qglob = qb + nt * 16 + g;
      float tmax = -1e30f;
#pragma unroll
      for (int mt = 0; mt < 8; mt++)
#pragma unroll
        for (int r = 0; r < 4; r++) {
          float v = st[mt][nt][r] * cs;
          if (diag && (kb + mt * 16 + q * 4 + r > qglob)) v = -1e30f;
          st[mt][nt][r] = v;
          tmax = fmaxf(tmax, v);
        }
      tmax = fmaxf(tmax, __shfl_xor(tmax, 16));
      tmax = fmaxf(tmax, __shfl_xor(tmax, 32));
      const float mnew = fmaxf(m_run[nt], tmax);
      const float alpha = __builtin_amdgcn_exp2f(m_run[nt] - mnew);
      float psum = 0.0f;
#pragma unroll
      for (int mt = 0; mt < 8; mt++)
#pragma unroll
        for (int r = 0; r < 4; r++) {
          float p = __builtin_amdgcn_exp2f(st[mt][nt][r] - mnew);
          st[mt][nt][r] = p;
          psum += p;
        }
      psum += __shfl_xor(psum, 16);
      psum += __shfl_xor(psum, 32);
      l_run[nt] = l_run[nt] * alpha + psum;
      m_run[nt] = mnew;
#pragma unroll
      for (int mt = 0; mt < 4; mt++) {
        ot[mt][nt][0] *= alpha; ot[mt][nt][1] *= alpha;
        ot[mt][nt][2] *= alpha; ot[mt][nt][3] *= alpha;
      }
      short* Pw = &Ps[wave][0];
#pragma unroll
      for (int mt = 0; mt < 8; mt++) {
        short4_t pk;
#pragma unroll
        for (int r = 0; r < 4; r++) pk[r] = f2bf(st[mt][nt][r]);
        *(short4_t*)&Pw[(nt * 16 + g) * 136 + mt * 16 + q * 4] = pk;
      }
    }

    // O^T += V^T * P^T
#pragma unroll
    for (int kk = 0; kk < 4; kk++) {
      bf16x8 pb[2];
#pragma unroll
      for (int nt = 0; nt < 2; nt++)
        pb[nt] = *(const bf16x8*)&Ps[wave][(nt * 16 + g) * 136 + kk * 32 + q * 8];
#pragma unroll
      for (int mt = 0; mt < 4; mt++) {
        bf16x8 av = *(const bf16x8*)&VTs[(mt * 16 + g) * 136 + kk * 32 + q * 8];
#pragma unroll
        for (int nt = 0; nt < 2; nt++)
          ot[mt][nt] = __builtin_amdgcn_mfma_f32_16x16x32_bf16(av, pb[nt],
                                                               ot[mt][nt], 0, 0, 0);
      }
    }
  }

  // epilogue: O[b, qrow, h*64+d] = O^T / l
  const int b = bh >> 4, h = bh & 15;
#pragma unroll
  for (int nt = 0; nt < 2; nt++) {
    const float inv = 1.0f / l_run[nt];
    const int qrow = qt * 128 + wave * 32 + nt * 16 + g;
    size_t obase = ((size_t)b * 2048 + qrow) * 1024 + h * 64;
#pragma unroll
    for (int mt = 0; mt < 4; mt++) {
      short4_t ov;
#pragma unroll
      for (int r = 0; r < 4; r++) ov[r] = f2bf(ot[mt][nt][r] * inv);
      *(short4_t*)&Og[obase + mt * 16 + q * 4] = ov;
    }
  }
}

// ---------------- launch ----------------
extern "C" void kernel_launch(void* const* d_in, const int* in_sizes, int n_in,
                              void* d_out, int out_size, void* d_ws, size_t ws_size,
                              hipStream_t stream) {
  const float* x      = (const float*)d_in[0];   // [4,2048,1024]
  const float* w_qkv  = (const float*)d_in[1];   // [1024,3072]
  const float* w_proj = (const float*)d_in[2];   // [1024,1024]
  float* out = (float*)d_out;                    // [4,2048,1024]

  char* ws = (char*)d_ws;
  short* xb     = (short*)(ws);                    // 16 MB bf16 x; reused as O after QKV GEMM
  short* wqkvT  = (short*)(ws + 16777216);         // 6 MB
  short* wprojT = (short*)(ws + 23068672);         // 2 MB
  short* Qb     = (short*)(ws + 25165824);         // 16 MB  [B,H,T,D]
  short* Kb     = (short*)(ws + 41943040);         // 16 MB
  short* Vb     = (short*)(ws + 58720256);         // 16 MB  (total 72 MiB)

  convert_bf16<<<8192, 256, 0, stream>>>(x, xb);
  {
    dim3 gq(96, 32); transpose_bf16<<<gq, 256, 0, stream>>>(w_qkv, wqkvT, 1024, 3072);
    dim3 gp(32, 32); transpose_bf16<<<gp, 256, 0, stream>>>(w_proj, wprojT, 1024, 1024);
  }
  {
    dim3 g(24, 64);  // N/128, M/128
    gemm_bt<1><<<g, 256, 0, stream>>>(xb, wqkvT, nullptr, Qb, Kb, Vb, 8192, 3072, 1024);
  }
  {
    dim3 g(16, 64);  // q-tiles, b*h
    attn_fwd<<<g, 256, 0, stream>>>(Qb, Kb, Vb, xb /* O, reusing xb */);
  }
  {
    dim3 g(8, 64);
    gemm_bt<0><<<g, 256, 0, stream>>>(xb, wprojT, out, nullptr, nullptr, nullptr,
                                      8192, 1024, 1024);
  }
}

// Round 2
// 258.971 us; speedup vs baseline: 1.4784x; 1.4784x over previous
//
#include <hip/hip_runtime.h>
#include <cstdint>
#include <cstddef>
#include <type_traits>

typedef float  f32x4   __attribute__((ext_vector_type(4)));
typedef __bf16 bf16x8  __attribute__((ext_vector_type(8)));
typedef short  short4_t __attribute__((ext_vector_type(4)));
typedef short  short8_t __attribute__((ext_vector_type(8)));

// hw f32->bf16 (v_cvt_pk_bf16_f32 on gfx950), RNE
__device__ __forceinline__ short f2bf(float f) {
  return __builtin_bit_cast(short, (__bf16)f);
}

__device__ __forceinline__ void gl_lds16(const void* g, void* l) {
  __builtin_amdgcn_global_load_lds((const __attribute__((address_space(1))) void*)g,
                                   (__attribute__((address_space(3))) void*)l, 16, 0, 0);
}

// ---------------- elementwise fp32 -> bf16 ----------------
__global__ void convert_bf16(const float* __restrict__ X, short* __restrict__ Xb) {
  int i = (blockIdx.x * 256 + threadIdx.x) * 4;
  f32x4 v = *(const f32x4*)&X[i];
  short4_t o;
#pragma unroll
  for (int j = 0; j < 4; j++) o[j] = f2bf(v[j]);
  *(short4_t*)&Xb[i] = o;
}

// ---------------- transpose-convert W[K][N] fp32 -> WT[N][K] bf16 ----------------
__global__ void transpose_bf16(const float* __restrict__ W, short* __restrict__ WT,
                               int K, int N) {
  __shared__ float tile[32][33];
  int tx = threadIdx.x & 31, ty = threadIdx.x >> 5;    // ty 0..7
  int n0 = blockIdx.x * 32, k0 = blockIdx.y * 32;
#pragma unroll
  for (int i = 0; i < 32; i += 8)
    tile[ty + i][tx] = W[(size_t)(k0 + ty + i) * N + n0 + tx];
  __syncthreads();
#pragma unroll
  for (int i = 0; i < 32; i += 8)
    WT[(size_t)(n0 + ty + i) * K + k0 + tx] = f2bf(tile[tx][ty + i]);
}

// ---------------- m97-style bf16 GEMM, Bt is [N][K] ----------------
// MODE 0: fp32 out [M][N].
// MODE 1: scatter bf16 into Q [B,H,T,D], K [B,H,T,D], V^T [B,H,D,T].
template <int MODE>
__global__ __launch_bounds__(256, 2) void gemm_bt(
    const short* __restrict__ A, const short* __restrict__ Bt,
    float* __restrict__ outf, short* __restrict__ Qo, short* __restrict__ Ko,
    short* __restrict__ Vo, int M, int N, int K) {
  __shared__ alignas(16) short As[128 * 32];
  __shared__ alignas(16) short Bs[128 * 32];
  const int tid = threadIdx.x;
  const int lane = tid & 63;
  const int g = lane & 15, q = lane >> 4;
  const int wave = tid >> 6;
  const int m0 = blockIdx.y * 128, n0 = blockIdx.x * 128;
  const int wm = (wave >> 1) * 64, wn = (wave & 1) * 64;

  const int srow = tid >> 2;            // 0..63
  const int scol = (tid & 3) * 8;       // element col within BK
  const short* ap0 = A  + (size_t)(m0 + srow) * K + scol;
  const short* ap1 = A  + (size_t)(m0 + 64 + srow) * K + scol;
  const short* bp0 = Bt + (size_t)(n0 + srow) * K + scol;
  const short* bp1 = Bt + (size_t)(n0 + 64 + srow) * K + scol;
  short* la0 = &As[tid * 8];
  short* la1 = &As[(tid + 256) * 8];
  short* lb0 = &Bs[tid * 8];
  short* lb1 = &Bs[(tid + 256) * 8];

  f32x4 acc[4][4] = {};

  for (int k0 = 0; k0 < K; k0 += 32) {
    __syncthreads();
    gl_lds16(ap0 + k0, la0);
    gl_lds16(ap1 + k0, la1);
    gl_lds16(bp0 + k0, lb0);
    gl_lds16(bp1 + k0, lb1);
    __syncthreads();
    bf16x8 af[4], bfr[4];
#pragma unroll
    for (int mt = 0; mt < 4; mt++)
      af[mt] = *(const bf16x8*)&As[(wm + mt * 16 + g) * 32 + q * 8];
#pragma unroll
    for (int nt = 0; nt < 4; nt++)
      bfr[nt] = *(const bf16x8*)&Bs[(wn + nt * 16 + g) * 32 + q * 8];
#pragma unroll
    for (int mt = 0; mt < 4; mt++)
#pragma unroll
      for (int nt = 0; nt < 4; nt++)
        acc[mt][nt] = __builtin_amdgcn_mfma_f32_16x16x32_bf16(af[mt], bfr[nt],
                                                              acc[mt][nt], 0, 0, 0);
  }

  if (MODE == 0) {
#pragma unroll
    for (int mt = 0; mt < 4; mt++)
#pragma unroll
      for (int nt = 0; nt < 4; nt++) {
        int n = n0 + wn + nt * 16 + g;
        int mbase = m0 + wm + mt * 16 + q * 4;
#pragma unroll
        for (int r = 0; r < 4; r++)
          outf[(size_t)(mbase + r) * N + n] = acc[mt][nt][r];
      }
  } else {
#pragma unroll
    for (int nt = 0; nt < 4; nt++) {
      int n = n0 + wn + nt * 16 + g;
      int which = n >> 10;            // 0=q 1=k 2=v
      int c = n & 1023;
      int h = c >> 6, d = c & 63;
#pragma unroll
      for (int mt = 0; mt < 4; mt++) {
        int mbase = m0 + wm + mt * 16 + q * 4;
        int b = mbase >> 11, t = mbase & 2047;   // 4 rows never cross b
        if (which == 2) {
          // V^T: [b,h,d,t] — t consecutive over r -> packed 8B store
          short4_t pv;
#pragma unroll
          for (int r = 0; r < 4; r++) pv[r] = f2bf(acc[mt][nt][r]);
          *(short4_t*)&Vo[((size_t)((b << 4) + h) * 64 + d) * 2048 + t] = pv;
        } else {
          short* dst = (which == 0) ? Qo : Ko;
#pragma unroll
          for (int r = 0; r < 4; r++)
            dst[((size_t)((b << 4) + h) * 2048 + (t + r)) * 64 + d] =
                f2bf(acc[mt][nt][r]);
        }
      }
    }
  }
}

// ---------------- causal flash attention ----------------
// Q,K: [B,H,T,D] bf16.  Vt: [B,H,D,T] bf16.  O: [B,T,H*D] bf16.
// Block = one (b,h) + paired q-tiles (qt, 15-qt): uniform 17 k-iterations.
// S^T = K*Q^T puts q-rows in C-layout columns: 2-shuffle softmax reduce,
// row-packed P stores. Q pre-scaled by (1/sqrt(D))*log2(e). Diagonal
// iteration peeled (masking VALU only where needed). Next K/V tile
// prefetched into registers across the compute phase.
__global__ __launch_bounds__(256, 2) void attn_fwd(
    const short* __restrict__ Qg, const short* __restrict__ Kg,
    const short* __restrict__ Vt, short* __restrict__ Og) {
  __shared__ alignas(16) short Ps[4][32 * 136];   // per-wave P [32][128+8]; Q staging
  __shared__ alignas(16) short Ks[128 * 72];      // K tile [128][64+8]
  __shared__ alignas(16) short VTs[64 * 136];     // V^T [64][128+8]

  const int tid = threadIdx.x, lane = tid & 63, wave = tid >> 6;
  const int g = lane & 15, q = lane >> 4;
  const int bh = blockIdx.y;
  const size_t base = (size_t)bh * (2048 * 64);
  const int b = bh >> 4, h = bh & 15;
  const float cs = 0.18033688011f;     // (1/sqrt(64)) * log2(e)

  short8_t kreg[4], vreg[4];
  auto loadKV = [&](int kt) {
    const short* Kp  = Kg + base + (size_t)kt * 128 * 64;
    const short* Vtp = Vt + base + (size_t)kt * 128;
#pragma unroll
    for (int i = 0; i < 4; i++) {
      int c = tid + i * 256;
      kreg[i] = *(const short8_t*)&Kp[(c >> 3) * 64 + (c & 7) * 8];
      vreg[i] = *(const short8_t*)&Vtp[(size_t)(c >> 4) * 2048 + (c & 15) * 8];
    }
  };
  auto storeKV = [&]() {
#pragma unroll
    for (int i = 0; i < 4; i++) {
      int c = tid + i * 256;
      *(short8_t*)&Ks[(c >> 3) * 72 + (c & 7) * 8] = kreg[i];
      *(short8_t*)&VTs[(c >> 4) * 136 + (c & 15) * 8] = vreg[i];
    }
  };

  for (int half = 0; half < 2; half++) {
    const int qt = (half == 0) ? (int)blockIdx.x : 15 - (int)blockIdx.x;

    // ---- stage Q tile (reuses Ps region), pull pre-scaled frags ----
    __syncthreads();                       // protect Ps reuse from prior half
    {
      const short* Qp = Qg + base + (size_t)qt * 128 * 64;
      short* Qs = &Ps[0][0];
#pragma unroll
      for (int i = 0; i < 4; i++) {
        int c = tid + i * 256;
        *(short8_t*)&Qs[(c >> 3) * 72 + (c & 7) * 8] =
            *(const short8_t*)&Qp[(c >> 3) * 64 + (c & 7) * 8];
      }
    }
    __syncthreads();
    bf16x8 bq[2][2];
#pragma unroll
    for (int nt = 0; nt < 2; nt++)
#pragma unroll
      for (int kk = 0; kk < 2; kk++) {
        bf16x8 v = *(const bf16x8*)&Ps[0][(wave * 32 + nt * 16 + g) * 72 + kk * 32 + q * 8];
#pragma unroll
        for (int j = 0; j < 8; j++) v[j] = (__bf16)((float)v[j] * cs);
        bq[nt][kk] = v;
      }

    f32x4 ot[4][2] = {};                 // O^T acc: [d-tiles 4][qrow-tiles 2]
    float m_run[2] = {-1e30f, -1e30f};
    float l_run[2] = {0.0f, 0.0f};

    auto compute = [&](auto diagc, int kt) {
      constexpr bool DIAG = decltype(diagc)::value;
      // S^T = K * Q^T : rows=keys (8 tiles), cols=qrows (2 tiles)
      f32x4 st[8][2] = {};
#pragma unroll
      for (int kk = 0; kk < 2; kk++)
#pragma unroll
        for (int mt = 0; mt < 8; mt++) {
          bf16x8 ak = *(const bf16x8*)&Ks[(mt * 16 + g) * 72 + kk * 32 + q * 8];
#pragma unroll
          for (int nt = 0; nt < 2; nt++)
            st[mt][nt] = __builtin_amdgcn_mfma_f32_16x16x32_bf16(ak, bq[nt][kk],
                                                                 st[mt][nt], 0, 0, 0);
        }

#pragma unroll
      for (int nt = 0; nt < 2; nt++) {
        const int qloc = wave * 32 + nt * 16 + g;   // q-row within tile
        float tmax = -1e30f;
#pragma unroll
        for (int mt = 0; mt < 8; mt++)
#pragma unroll
          for (int r = 0; r < 4; r++) {
            if (DIAG) {
              if (mt * 16 + q * 4 + r > qloc) st[mt][nt][r] = -1e30f;
            }
            tmax = fmaxf(tmax, st[mt][nt][r]);
          }
        tmax = fmaxf(tmax, __shfl_xor(tmax, 16));
        tmax = fmaxf(tmax, __shfl_xor(tmax, 32));
        const float mnew = fmaxf(m_run[nt], tmax);
        const float alpha = __builtin_amdgcn_exp2f(m_run[nt] - mnew);
        float psum = 0.0f;
        short* Pw = &Ps[wave][0];
#pragma unroll
        for (int mt = 0; mt < 8; mt++) {
          short4_t pk;
#pragma unroll
          for (int r = 0; r < 4; r++) {
            float p = __builtin_amdgcn_exp2f(st[mt][nt][r] - mnew);
            psum += p;
            pk[r] = f2bf(p);
          }
          *(short4_t*)&Pw[(nt * 16 + g) * 136 + mt * 16 + q * 4] = pk;
        }
        psum += __shfl_xor(psum, 16);
        psum += __shfl_xor(psum, 32);
        l_run[nt] = l_run[nt] * alpha + psum;
        m_run[nt] = mnew;
#pragma unroll
        for (int mt = 0; mt < 4; mt++) {
          ot[mt][nt][0] *= alpha; ot[mt][nt][1] *= alpha;
          ot[mt][nt][2] *= alpha; ot[mt][nt][3] *= alpha;
        }
      }

      // O^T += V^T * P^T   (P read back same-wave only; lgkmcnt handles dep)
#pragma unroll
      for (int kk = 0; kk < 4; kk++) {
        bf16x8 pb[2];
#pragma unroll
        for (int nt = 0; nt < 2; nt++)
          pb[nt] = *(const bf16x8*)&Ps[wave][(nt * 16 + g) * 136 + kk * 32 + q * 8];
#pragma unroll
        for (int mt = 0; mt < 4; mt++) {
          bf16x8 av = *(const bf16x8*)&VTs[(mt * 16 + g) * 136 + kk * 32 + q * 8];
#pragma unroll
          for (int nt = 0; nt < 2; nt++)
            ot[mt][nt] = __builtin_amdgcn_mfma_f32_16x16x32_bf16(av, pb[nt],
                                                                 ot[mt][nt], 0, 0, 0);
        }
      }
    };

    loadKV(0);
    for (int kt = 0; kt < qt; kt++) {      // off-diagonal: no masking
      __syncthreads();
      storeKV();
      loadKV(kt + 1);                      // prefetch overlaps compute
      __syncthreads();
      compute(std::integral_constant<bool, false>{}, kt);
    }
    __syncthreads();                       // diagonal iteration
    storeKV();
    __syncthreads();
    compute(std::integral_constant<bool, true>{}, qt);

    // ---- epilogue: O[b, qrow, h*64+d] = O^T / l ----
#pragma unroll
    for (int nt = 0; nt < 2; nt++) {
      const float inv = 1.0f / l_run[nt];
      const int qrow = qt * 128 + wave * 32 + nt * 16 + g;
      size_t obase = ((size_t)b * 2048 + qrow) * 1024 + h * 64;
#pragma unroll
      for (int mt = 0; mt < 4; mt++) {
        short4_t ov;
#pragma unroll
        for (int r = 0; r < 4; r++) ov[r] = f2bf(ot[mt][nt][r] * inv);
        *(short4_t*)&Og[obase + mt * 16 + q * 4] = ov;
      }
    }
  }
}

// ---------------- launch ----------------
extern "C" void kernel_launch(void* const* d_in, const int* in_sizes, int n_in,
                              void* d_out, int out_size, void* d_ws, size_t ws_size,
                              hipStream_t stream) {
  const float* x      = (const float*)d_in[0];   // [4,2048,1024]
  const float* w_qkv  = (const float*)d_in[1];   // [1024,3072]
  const float* w_proj = (const float*)d_in[2];   // [1024,1024]
  float* out = (float*)d_out;                    // [4,2048,1024]

  char* ws = (char*)d_ws;
  short* xb     = (short*)(ws);                    // 16 MB bf16 x; reused as O
  short* wqkvT  = (short*)(ws + 16777216);         // 6 MB
  short* wprojT = (short*)(ws + 23068672);         // 2 MB
  short* Qb     = (short*)(ws + 25165824);         // 16 MB  [B,H,T,D]
  short* Kb     = (short*)(ws + 41943040);         // 16 MB  [B,H,T,D]
  short* Vtb    = (short*)(ws + 58720256);         // 16 MB  [B,H,D,T]

  convert_bf16<<<8192, 256, 0, stream>>>(x, xb);
  {
    dim3 gq(96, 32); transpose_bf16<<<gq, 256, 0, stream>>>(w_qkv, wqkvT, 1024, 3072);
    dim3 gp(32, 32); transpose_bf16<<<gp, 256, 0, stream>>>(w_proj, wprojT, 1024, 1024);
  }
  {
    dim3 g(24, 64);  // N/128, M/128
    gemm_bt<1><<<g, 256, 0, stream>>>(xb, wqkvT, nullptr, Qb, Kb, Vtb, 8192, 3072, 1024);
  }
  {
    dim3 g(8, 64);   // paired q-tiles (qt, 15-qt), b*h
    attn_fwd<<<g, 256, 0, stream>>>(Qb, Kb, Vtb, xb /* O, reusing xb */);
  }
  {
    dim3 g(8, 64);
    gemm_bt<0><<<g, 256, 0, stream>>>(xb, wprojT, out, nullptr, nullptr, nullptr,
                                      8192, 1024, 1024);
  }
}